// Round 4
// baseline (813.153 us; speedup 1.0000x reference)
//
#include <hip/hip_runtime.h>
#include <hip/hip_bf16.h>

// Problem constants (from reference)
constexpr int NN = 50000;   // nodes
constexpr int EE = 800000;  // edges
constexpr int D_IN = 16;
constexpr int H = 128;
constexpr int D_OUT = 3;

// ---------------------------------------------------------------------------
// K0: detect whether edge_index arrived as int64 (reference dtype) or int32.
// Values < 2^31, so an int64 buffer has ALL odd int32 words == 0; an int32
// buffer has random src values at odd positions. Device-side only (graph-safe).
__global__ __launch_bounds__(1024) void detect_kernel(const int* __restrict__ e,
                                                      int* __restrict__ flag) {
    __shared__ int any_nonzero;
    if (threadIdx.x == 0) any_nonzero = 0;
    __syncthreads();
    if (e[2 * threadIdx.x + 1] != 0) atomicOr(&any_nonzero, 1);
    __syncthreads();
    if (threadIdx.x == 0) *flag = (any_nonzero == 0) ? 1 : 0;  // 1 => int64
}

// K1: zero the per-node edge counters
__global__ __launch_bounds__(256) void zero_counts_kernel(int* __restrict__ counts) {
    int i = blockIdx.x * 256 + threadIdx.x;
    if (i < NN) counts[i] = 0;
}

// K2: count in-degree (dst side), excluding the synthetic self loop
__global__ __launch_bounds__(256) void count_kernel(const int* __restrict__ e,
                                                    const int* __restrict__ flag,
                                                    int* __restrict__ counts) {
    int i = blockIdx.x * 256 + threadIdx.x;
    if (i >= EE) return;
    int f = *flag;  // uniform, cached
    int d = f ? e[2 * EE + 2 * i] : e[EE + i];
    atomicAdd(&counts[d], 1);
}

// K3: single-block exclusive scan over counts -> row_off / fill_pos; dinv
__global__ __launch_bounds__(1024) void scan_kernel(const int* __restrict__ counts,
                                                    int* __restrict__ row_off,
                                                    int* __restrict__ fill_pos,
                                                    float* __restrict__ dinv) {
    __shared__ int lds[1024];
    int t = threadIdx.x;
    const int C = (NN + 1023) / 1024;  // 49
    int begin = t * C;
    int end = begin + C; if (end > NN) end = NN;
    int sum = 0;
    for (int i = begin; i < end; ++i) sum += counts[i];
    lds[t] = sum;
    __syncthreads();
    // Hillis-Steele inclusive scan over 1024 partials
    for (int off = 1; off < 1024; off <<= 1) {
        int v = (t >= off) ? lds[t - off] : 0;
        __syncthreads();
        lds[t] += v;
        __syncthreads();
    }
    int run = lds[t] - sum;  // exclusive base for this chunk
    for (int i = begin; i < end; ++i) {
        row_off[i] = run;
        fill_pos[i] = run;
        int c = counts[i];
        dinv[i] = rsqrtf((float)(c + 1));  // +1 = self loop; deg >= 1 always
        run += c;
    }
    if (t == 1023) row_off[NN] = lds[1023];  // == EE
}

// K4: scatter edges into CSR buckets; precompute per-edge weight dinv[s]*dinv[d].
// (order within bucket nondeterministic; fp32 sum order tolerance OK)
__global__ __launch_bounds__(256) void fill_kernel(const int* __restrict__ e,
                                                   const int* __restrict__ flag,
                                                   int* __restrict__ fill_pos,
                                                   const float* __restrict__ dinv,
                                                   int* __restrict__ srcs,
                                                   float* __restrict__ wnorm) {
    int i = blockIdx.x * 256 + threadIdx.x;
    if (i >= EE) return;
    int f = *flag;
    int s = f ? e[2 * i]            : e[i];
    int d = f ? e[2 * EE + 2 * i]   : e[EE + i];
    int pos = atomicAdd(&fill_pos[d], 1);
    srcs[pos] = s;
    wnorm[pos] = dinv[s] * dinv[d];
}

// K5: encoder  h[n][j] = x[n][:] . enc_w[j][:] + enc_b[j]
// 32 nodes per block; W/bias/x all staged in LDS (x traffic exact, w ~12 MB total).
constexpr int ENC_NPB = 32;
__global__ __launch_bounds__(256) void encoder_kernel(const float* __restrict__ x,
                                                      const float* __restrict__ w,
                                                      const float* __restrict__ b,
                                                      float* __restrict__ h) {
    __shared__ float wt[D_IN][H];        // transposed: wt[k][j]
    __shared__ float bs[H];
    __shared__ float xs[ENC_NPB][D_IN];
    int t = threadIdx.x;
    for (int i = t; i < H * D_IN; i += 256) {
        int j = i >> 4, k = i & 15;
        wt[k][j] = w[i];
    }
    if (t < H) bs[t] = b[t];
    int n0 = blockIdx.x * ENC_NPB;
    // coalesced x stage: 512 consecutive floats
    for (int i = t; i < ENC_NPB * D_IN; i += 256) {
        int n = n0 + (i >> 4);
        xs[i >> 4][i & 15] = (n < NN) ? x[(size_t)n0 * D_IN + i] : 0.f;
    }
    __syncthreads();
    int j = t & 127;      // feature
    int half = t >> 7;    // 0/1
    for (int r = half; r < ENC_NPB; r += 2) {
        int n = n0 + r;
        if (n >= NN) break;
        float acc = bs[j];
#pragma unroll
        for (int k = 0; k < D_IN; ++k) acc += xs[r][k] * wt[k][j];
        h[(size_t)n * H + j] = acc;
    }
}

// K6: conv GEMM  hw = h @ W^T   (W: [H][H] row-major)
// 32 rows/block, 256 threads, 4x4 register tile, transposed LDS h-tile.
__global__ __launch_bounds__(256) void gemm_h_kernel(const float* __restrict__ hin,
                                                     const float* __restrict__ w,
                                                     float* __restrict__ hw) {
    __shared__ float ht[128][36];  // ht[k][r]; stride 36 keeps float4 reads 16B-aligned
    int t = threadIdx.x;
    int n0 = blockIdx.x * 32;
#pragma unroll
    for (int i = 0; i < 4; ++i) {
        int idx = t + i * 256;      // 0..1023
        int row = idx >> 5;         // 0..31
        int c4 = (idx & 31) << 2;   // 0,4,..,124
        int n = n0 + row;
        float4 v = make_float4(0.f, 0.f, 0.f, 0.f);
        if (n < NN) v = *reinterpret_cast<const float4*>(hin + (size_t)n * H + c4);
        ht[c4 + 0][row] = v.x;
        ht[c4 + 1][row] = v.y;
        ht[c4 + 2][row] = v.z;
        ht[c4 + 3][row] = v.w;
    }
    __syncthreads();
    int tx = t & 31, ty = t >> 5;
    int j0 = tx << 2, r0 = ty << 2;  // 4 output cols, 4 rows per thread
    float acc[4][4] = {};            // acc[ri][ji]
    const float* wbase = w + j0 * H;
    for (int k = 0; k < 128; k += 4) {
        float a[4][4];  // a[kk][ri]
#pragma unroll
        for (int kk = 0; kk < 4; ++kk)
            *reinterpret_cast<float4*>(a[kk]) =
                *reinterpret_cast<const float4*>(&ht[k + kk][r0]);
#pragma unroll
        for (int ji = 0; ji < 4; ++ji) {
            float wv[4];
            *reinterpret_cast<float4*>(wv) =
                *reinterpret_cast<const float4*>(wbase + ji * H + k);
#pragma unroll
            for (int ri = 0; ri < 4; ++ri)
                acc[ri][ji] += a[0][ri] * wv[0] + a[1][ri] * wv[1] +
                               a[2][ri] * wv[2] + a[3][ri] * wv[3];
        }
    }
#pragma unroll
    for (int ri = 0; ri < 4; ++ri) {
        int n = n0 + r0 + ri;
        if (n < NN)
            *reinterpret_cast<float4*>(hw + (size_t)n * H + j0) =
                make_float4(acc[ri][0], acc[ri][1], acc[ri][2], acc[ri][3]);
    }
}

// K7: aggregation. One wave per node; lane owns features {2*lane, 2*lane+1} (float2).
// Fuses: edge gather+scale (precomputed wnorm), self-loop term, bias, ReLU.
// No atomics, no zeroing. unroll-4: batch index/weight loads -> 4 independent
// gathers in flight per wave (dependent-chain latency hiding).
__global__ __launch_bounds__(256) void agg_kernel(const float* __restrict__ hw,
                                                  const int* __restrict__ row_off,
                                                  const int* __restrict__ srcs,
                                                  const float* __restrict__ wnorm,
                                                  const float* __restrict__ dinv,
                                                  const float* __restrict__ b,
                                                  float* __restrict__ hout) {
    int wid = (blockIdx.x * 256 + threadIdx.x) >> 6;  // node id
    int lane = threadIdx.x & 63;
    if (wid >= NN) return;
    const float2* hw2 = reinterpret_cast<const float2*>(hw);
    float dn = dinv[wid];
    float2 v = hw2[(size_t)wid * 64 + lane];
    float a0 = v.x * dn * dn;                 // appended self loop
    float a1 = v.y * dn * dn;
    int beg = row_off[wid], end = row_off[wid + 1];
#pragma unroll 4
    for (int j = beg; j < end; ++j) {
        int s = srcs[j];                        // wave-uniform streamed load
        float wgt = wnorm[j];                   // wave-uniform streamed load
        float2 u = hw2[(size_t)s * 64 + lane];  // 512B/wave coalesced gather
        a0 += wgt * u.x;
        a1 += wgt * u.y;
    }
    float2 bb = reinterpret_cast<const float2*>(b)[lane];
    float2 o;
    o.x = fmaxf(a0 + bb.x, 0.f);
    o.y = fmaxf(a1 + bb.y, 0.f);
    reinterpret_cast<float2*>(hout)[(size_t)wid * 64 + lane] = o;
}

// K8: decoder  out[n][k] = h[n][:] . dec_w[k][:] + dec_b[k]; one wave per node
__global__ __launch_bounds__(256) void decoder_kernel(const float* __restrict__ h,
                                                      const float* __restrict__ w,
                                                      const float* __restrict__ b,
                                                      float* __restrict__ out) {
    int wid = (blockIdx.x * 256 + threadIdx.x) >> 6;
    int lane = threadIdx.x & 63;
    if (wid >= NN) return;
    float h0 = h[(size_t)wid * H + lane];
    float h1 = h[(size_t)wid * H + lane + 64];
    float p0 = h0 * w[0 * H + lane] + h1 * w[0 * H + lane + 64];
    float p1 = h0 * w[1 * H + lane] + h1 * w[1 * H + lane + 64];
    float p2 = h0 * w[2 * H + lane] + h1 * w[2 * H + lane + 64];
#pragma unroll
    for (int off = 32; off >= 1; off >>= 1) {
        p0 += __shfl_down(p0, off, 64);
        p1 += __shfl_down(p1, off, 64);
        p2 += __shfl_down(p2, off, 64);
    }
    if (lane == 0) {
        out[wid * 3 + 0] = p0 + b[0];
        out[wid * 3 + 1] = p1 + b[1];
        out[wid * 3 + 2] = p2 + b[2];
    }
}

extern "C" void kernel_launch(void* const* d_in, const int* in_sizes, int n_in,
                              void* d_out, int out_size, void* d_ws, size_t ws_size,
                              hipStream_t stream) {
    const float* x      = (const float*)d_in[0];
    const int*   eidx   = (const int*)d_in[1];   // [2][E]; int32 or int64 (detected)
    const float* enc_w  = (const float*)d_in[2];
    const float* enc_b  = (const float*)d_in[3];
    const float* conv_w = (const float*)d_in[4]; // [3][H][H]
    const float* conv_b = (const float*)d_in[5]; // [3][H]
    const float* dec_w  = (const float*)d_in[6];
    const float* dec_b  = (const float*)d_in[7];
    float* out = (float*)d_out;

    // workspace carve-out (256B aligned); total ~59 MB
    char* ws = (char*)d_ws;
    auto alloc = [&](size_t bytes) -> char* {
        char* p = ws;
        ws += (bytes + 255) & ~(size_t)255;
        return p;
    };
    int*   flag     = (int*)alloc(256);
    int*   counts   = (int*)alloc((size_t)NN * 4);
    int*   row_off  = (int*)alloc((size_t)(NN + 1) * 4);
    int*   fill_pos = (int*)alloc((size_t)NN * 4);
    float* dinv     = (float*)alloc((size_t)NN * 4);
    int*   srcs     = (int*)alloc((size_t)EE * 4);
    float* wnorm    = (float*)alloc((size_t)EE * 4);
    float* hbuf     = (float*)alloc((size_t)NN * H * 4);
    float* hwbuf    = (float*)alloc((size_t)NN * H * 4);

    const int egrid = (EE + 255) / 256;          // 3125
    const int ngrid = (NN + 255) / 256;          // 196
    const int wgrid = (NN + 3) / 4;              // 12500 (4 waves/block)

    // CSR build (once; reused by all 3 layers)
    detect_kernel<<<1, 1024, 0, stream>>>(eidx, flag);
    zero_counts_kernel<<<ngrid, 256, 0, stream>>>(counts);
    count_kernel<<<egrid, 256, 0, stream>>>(eidx, flag, counts);
    scan_kernel<<<1, 1024, 0, stream>>>(counts, row_off, fill_pos, dinv);
    fill_kernel<<<egrid, 256, 0, stream>>>(eidx, flag, fill_pos, dinv, srcs, wnorm);

    // encoder
    encoder_kernel<<<(NN + ENC_NPB - 1) / ENC_NPB, 256, 0, stream>>>(x, enc_w, enc_b, hbuf);

    // 3 GCN layers: hbuf -> hwbuf (GEMM) -> hbuf (agg+relu)
    const int ggrid = (NN + 31) / 32;            // 1563
    for (int layer = 0; layer < 3; ++layer) {
        gemm_h_kernel<<<ggrid, 256, 0, stream>>>(hbuf, conv_w + (size_t)layer * H * H, hwbuf);
        agg_kernel<<<wgrid, 256, 0, stream>>>(hwbuf, row_off, srcs, wnorm, dinv,
                                              conv_b + (size_t)layer * H, hbuf);
    }

    // decoder
    decoder_kernel<<<wgrid, 256, 0, stream>>>(hbuf, dec_w, dec_b, out);
}

// Round 6
// 690.740 us; speedup vs baseline: 1.1772x; 1.1772x over previous
//
#include <hip/hip_runtime.h>
#include <hip/hip_bf16.h>

// Problem constants (from reference)
constexpr int NN = 50000;   // nodes
constexpr int EE = 800000;  // edges
constexpr int D_IN = 16;
constexpr int H = 128;
constexpr int D_OUT = 3;
constexpr int NB = (NN + 255) / 256;  // 196 scan blocks

// ---------------------------------------------------------------------------
// K0: detect whether edge_index arrived as int64 (reference dtype) or int32.
// Values < 2^31, so an int64 buffer has ALL odd int32 words == 0; an int32
// buffer has random src values at odd positions. Device-side only (graph-safe).
__global__ __launch_bounds__(1024) void detect_kernel(const int* __restrict__ e,
                                                      int* __restrict__ flag) {
    __shared__ int any_nonzero;
    if (threadIdx.x == 0) any_nonzero = 0;
    __syncthreads();
    if (e[2 * threadIdx.x + 1] != 0) atomicOr(&any_nonzero, 1);
    __syncthreads();
    if (threadIdx.x == 0) *flag = (any_nonzero == 0) ? 1 : 0;  // 1 => int64
}

// K1: zero the per-node edge counters
__global__ __launch_bounds__(256) void zero_counts_kernel(int* __restrict__ counts) {
    int i = blockIdx.x * 256 + threadIdx.x;
    if (i < NN) counts[i] = 0;
}

// K2: count in-degree (dst side), excluding the synthetic self loop
__global__ __launch_bounds__(256) void count_kernel(const int* __restrict__ e,
                                                    const int* __restrict__ flag,
                                                    int* __restrict__ counts) {
    int i = blockIdx.x * 256 + threadIdx.x;
    if (i >= EE) return;
    int f = *flag;  // uniform, cached
    int d = f ? e[2 * EE + 2 * i] : e[EE + i];
    atomicAdd(&counts[d], 1);
}

// K3a: per-block sums of counts (coalesced; wave+LDS reduce)
__global__ __launch_bounds__(256) void block_sum_kernel(const int* __restrict__ counts,
                                                        int* __restrict__ blocksums) {
    int t = threadIdx.x;
    int i = blockIdx.x * 256 + t;
    int c = (i < NN) ? counts[i] : 0;
#pragma unroll
    for (int off = 32; off >= 1; off >>= 1) c += __shfl_down(c, off, 64);
    __shared__ int ws[4];
    if ((t & 63) == 0) ws[t >> 6] = c;
    __syncthreads();
    if (t == 0) blocksums[blockIdx.x] = ws[0] + ws[1] + ws[2] + ws[3];
}

// K3b: single-block scan over the 196 block sums -> exclusive block offsets
__global__ __launch_bounds__(256) void block_scan_kernel(const int* __restrict__ blocksums,
                                                         int* __restrict__ blockoff,
                                                         int* __restrict__ row_off) {
    __shared__ int lds[256];
    int t = threadIdx.x;
    int s = (t < NB) ? blocksums[t] : 0;
    lds[t] = s;
    __syncthreads();
    for (int off = 1; off < 256; off <<= 1) {
        int v = (t >= off) ? lds[t - off] : 0;
        __syncthreads();
        lds[t] += v;
        __syncthreads();
    }
    if (t < NB) blockoff[t] = lds[t] - s;   // exclusive
    if (t == 255) row_off[NN] = lds[255];   // == EE
}

// K3c: per-block local exclusive scan + block offset -> row_off/fill_pos/dinv
__global__ __launch_bounds__(256) void block_scan_apply_kernel(const int* __restrict__ counts,
                                                               const int* __restrict__ blockoff,
                                                               int* __restrict__ row_off,
                                                               int* __restrict__ fill_pos,
                                                               float* __restrict__ dinv) {
    __shared__ int lds[256];
    int t = threadIdx.x;
    int i = blockIdx.x * 256 + t;
    int c = (i < NN) ? counts[i] : 0;
    lds[t] = c;
    __syncthreads();
    for (int off = 1; off < 256; off <<= 1) {
        int v = (t >= off) ? lds[t - off] : 0;
        __syncthreads();
        lds[t] += v;
        __syncthreads();
    }
    if (i < NN) {
        int excl = lds[t] - c + blockoff[blockIdx.x];
        row_off[i] = excl;
        fill_pos[i] = excl;
        dinv[i] = rsqrtf((float)(c + 1));  // +1 = self loop; deg >= 1 always
    }
}

// K4: scatter edges into CSR buckets; precompute per-edge weight dinv[s]*dinv[d].
// (order within bucket nondeterministic; fp32 sum order tolerance OK)
__global__ __launch_bounds__(256) void fill_kernel(const int* __restrict__ e,
                                                   const int* __restrict__ flag,
                                                   int* __restrict__ fill_pos,
                                                   const float* __restrict__ dinv,
                                                   int* __restrict__ srcs,
                                                   float* __restrict__ wnorm) {
    int i = blockIdx.x * 256 + threadIdx.x;
    if (i >= EE) return;
    int f = *flag;
    int s = f ? e[2 * i]            : e[i];
    int d = f ? e[2 * EE + 2 * i]   : e[EE + i];
    int pos = atomicAdd(&fill_pos[d], 1);
    srcs[pos] = s;
    wnorm[pos] = dinv[s] * dinv[d];
}

// K5: encoder  h[n][j] = x[n][:] . enc_w[j][:] + enc_b[j]
// 32 nodes per block; W/bias/x all staged in LDS (x traffic exact, w ~12 MB total).
constexpr int ENC_NPB = 32;
__global__ __launch_bounds__(256) void encoder_kernel(const float* __restrict__ x,
                                                      const float* __restrict__ w,
                                                      const float* __restrict__ b,
                                                      float* __restrict__ h) {
    __shared__ float wt[D_IN][H];        // transposed: wt[k][j]
    __shared__ float bs[H];
    __shared__ float xs[ENC_NPB][D_IN];
    int t = threadIdx.x;
    for (int i = t; i < H * D_IN; i += 256) {
        int j = i >> 4, k = i & 15;
        wt[k][j] = w[i];
    }
    if (t < H) bs[t] = b[t];
    int n0 = blockIdx.x * ENC_NPB;
    // coalesced x stage: 512 consecutive floats
    for (int i = t; i < ENC_NPB * D_IN; i += 256) {
        int n = n0 + (i >> 4);
        xs[i >> 4][i & 15] = (n < NN) ? x[(size_t)n0 * D_IN + i] : 0.f;
    }
    __syncthreads();
    int j = t & 127;      // feature
    int half = t >> 7;    // 0/1
    for (int r = half; r < ENC_NPB; r += 2) {
        int n = n0 + r;
        if (n >= NN) break;
        float acc = bs[j];
#pragma unroll
        for (int k = 0; k < D_IN; ++k) acc += xs[r][k] * wt[k][j];
        h[(size_t)n * H + j] = acc;
    }
}

// K6: conv GEMM  hw = h @ W^T   (W: [H][H] row-major)
// 32 rows/block, 256 threads, 4x4 register tile, transposed LDS h-tile.
__global__ __launch_bounds__(256) void gemm_h_kernel(const float* __restrict__ hin,
                                                     const float* __restrict__ w,
                                                     float* __restrict__ hw) {
    __shared__ float ht[128][36];  // ht[k][r]; stride 36 keeps float4 reads 16B-aligned
    int t = threadIdx.x;
    int n0 = blockIdx.x * 32;
#pragma unroll
    for (int i = 0; i < 4; ++i) {
        int idx = t + i * 256;      // 0..1023
        int row = idx >> 5;         // 0..31
        int c4 = (idx & 31) << 2;   // 0,4,..,124
        int n = n0 + row;
        float4 v = make_float4(0.f, 0.f, 0.f, 0.f);
        if (n < NN) v = *reinterpret_cast<const float4*>(hin + (size_t)n * H + c4);
        ht[c4 + 0][row] = v.x;
        ht[c4 + 1][row] = v.y;
        ht[c4 + 2][row] = v.z;
        ht[c4 + 3][row] = v.w;
    }
    __syncthreads();
    int tx = t & 31, ty = t >> 5;
    int j0 = tx << 2, r0 = ty << 2;  // 4 output cols, 4 rows per thread
    float acc[4][4] = {};            // acc[ri][ji]
    const float* wbase = w + j0 * H;
    for (int k = 0; k < 128; k += 4) {
        float a[4][4];  // a[kk][ri]
#pragma unroll
        for (int kk = 0; kk < 4; ++kk)
            *reinterpret_cast<float4*>(a[kk]) =
                *reinterpret_cast<const float4*>(&ht[k + kk][r0]);
#pragma unroll
        for (int ji = 0; ji < 4; ++ji) {
            float wv[4];
            *reinterpret_cast<float4*>(wv) =
                *reinterpret_cast<const float4*>(wbase + ji * H + k);
#pragma unroll
            for (int ri = 0; ri < 4; ++ri)
                acc[ri][ji] += a[0][ri] * wv[0] + a[1][ri] * wv[1] +
                               a[2][ri] * wv[2] + a[3][ri] * wv[3];
        }
    }
#pragma unroll
    for (int ri = 0; ri < 4; ++ri) {
        int n = n0 + r0 + ri;
        if (n < NN)
            *reinterpret_cast<float4*>(hw + (size_t)n * H + j0) =
                make_float4(acc[ri][0], acc[ri][1], acc[ri][2], acc[ri][3]);
    }
}

// K7: aggregation. One wave per node; lane owns features {2*lane, 2*lane+1} (float2).
// Fuses: edge gather+scale (precomputed wnorm), self-loop term, bias, ReLU.
// No atomics, no zeroing. unroll-4: batch index/weight loads -> 4 independent
// gathers in flight per wave (dependent-chain latency hiding).
__global__ __launch_bounds__(256) void agg_kernel(const float* __restrict__ hw,
                                                  const int* __restrict__ row_off,
                                                  const int* __restrict__ srcs,
                                                  const float* __restrict__ wnorm,
                                                  const float* __restrict__ dinv,
                                                  const float* __restrict__ b,
                                                  float* __restrict__ hout) {
    int wid = (blockIdx.x * 256 + threadIdx.x) >> 6;  // node id
    int lane = threadIdx.x & 63;
    if (wid >= NN) return;
    const float2* hw2 = reinterpret_cast<const float2*>(hw);
    float dn = dinv[wid];
    float2 v = hw2[(size_t)wid * 64 + lane];
    float a0 = v.x * dn * dn;                 // appended self loop
    float a1 = v.y * dn * dn;
    int beg = row_off[wid], end = row_off[wid + 1];
#pragma unroll 4
    for (int j = beg; j < end; ++j) {
        int s = srcs[j];                        // wave-uniform streamed load
        float wgt = wnorm[j];                   // wave-uniform streamed load
        float2 u = hw2[(size_t)s * 64 + lane];  // 512B/wave coalesced gather
        a0 += wgt * u.x;
        a1 += wgt * u.y;
    }
    float2 bb = reinterpret_cast<const float2*>(b)[lane];
    float2 o;
    o.x = fmaxf(a0 + bb.x, 0.f);
    o.y = fmaxf(a1 + bb.y, 0.f);
    reinterpret_cast<float2*>(hout)[(size_t)wid * 64 + lane] = o;
}

// K8: decoder  out[n][k] = h[n][:] . dec_w[k][:] + dec_b[k]; one wave per node
__global__ __launch_bounds__(256) void decoder_kernel(const float* __restrict__ h,
                                                      const float* __restrict__ w,
                                                      const float* __restrict__ b,
                                                      float* __restrict__ out) {
    int wid = (blockIdx.x * 256 + threadIdx.x) >> 6;
    int lane = threadIdx.x & 63;
    if (wid >= NN) return;
    float h0 = h[(size_t)wid * H + lane];
    float h1 = h[(size_t)wid * H + lane + 64];
    float p0 = h0 * w[0 * H + lane] + h1 * w[0 * H + lane + 64];
    float p1 = h0 * w[1 * H + lane] + h1 * w[1 * H + lane + 64];
    float p2 = h0 * w[2 * H + lane] + h1 * w[2 * H + lane + 64];
#pragma unroll
    for (int off = 32; off >= 1; off >>= 1) {
        p0 += __shfl_down(p0, off, 64);
        p1 += __shfl_down(p1, off, 64);
        p2 += __shfl_down(p2, off, 64);
    }
    if (lane == 0) {
        out[wid * 3 + 0] = p0 + b[0];
        out[wid * 3 + 1] = p1 + b[1];
        out[wid * 3 + 2] = p2 + b[2];
    }
}

extern "C" void kernel_launch(void* const* d_in, const int* in_sizes, int n_in,
                              void* d_out, int out_size, void* d_ws, size_t ws_size,
                              hipStream_t stream) {
    const float* x      = (const float*)d_in[0];
    const int*   eidx   = (const int*)d_in[1];   // [2][E]; int32 or int64 (detected)
    const float* enc_w  = (const float*)d_in[2];
    const float* enc_b  = (const float*)d_in[3];
    const float* conv_w = (const float*)d_in[4]; // [3][H][H]
    const float* conv_b = (const float*)d_in[5]; // [3][H]
    const float* dec_w  = (const float*)d_in[6];
    const float* dec_b  = (const float*)d_in[7];
    float* out = (float*)d_out;

    // workspace carve-out (256B aligned); total ~59 MB
    char* ws = (char*)d_ws;
    auto alloc = [&](size_t bytes) -> char* {
        char* p = ws;
        ws += (bytes + 255) & ~(size_t)255;
        return p;
    };
    int*   flag      = (int*)alloc(256);
    int*   counts    = (int*)alloc((size_t)NN * 4);
    int*   blocksums = (int*)alloc((size_t)NB * 4);
    int*   blockoff  = (int*)alloc((size_t)NB * 4);
    int*   row_off   = (int*)alloc((size_t)(NN + 1) * 4);
    int*   fill_pos  = (int*)alloc((size_t)NN * 4);
    float* dinv      = (float*)alloc((size_t)NN * 4);
    int*   srcs      = (int*)alloc((size_t)EE * 4);
    float* wnorm     = (float*)alloc((size_t)EE * 4);
    float* hbuf      = (float*)alloc((size_t)NN * H * 4);
    float* hwbuf     = (float*)alloc((size_t)NN * H * 4);

    const int egrid = (EE + 255) / 256;          // 3125
    const int wgrid = (NN + 3) / 4;              // 12500 (4 waves/block)

    // CSR build (once; reused by all 3 layers)
    detect_kernel<<<1, 1024, 0, stream>>>(eidx, flag);
    zero_counts_kernel<<<NB, 256, 0, stream>>>(counts);
    count_kernel<<<egrid, 256, 0, stream>>>(eidx, flag, counts);
    block_sum_kernel<<<NB, 256, 0, stream>>>(counts, blocksums);
    block_scan_kernel<<<1, 256, 0, stream>>>(blocksums, blockoff, row_off);
    block_scan_apply_kernel<<<NB, 256, 0, stream>>>(counts, blockoff, row_off, fill_pos, dinv);
    fill_kernel<<<egrid, 256, 0, stream>>>(eidx, flag, fill_pos, dinv, srcs, wnorm);

    // encoder
    encoder_kernel<<<(NN + ENC_NPB - 1) / ENC_NPB, 256, 0, stream>>>(x, enc_w, enc_b, hbuf);

    // 3 GCN layers: hbuf -> hwbuf (GEMM) -> hbuf (agg+relu)
    const int ggrid = (NN + 31) / 32;            // 1563
    for (int layer = 0; layer < 3; ++layer) {
        gemm_h_kernel<<<ggrid, 256, 0, stream>>>(hbuf, conv_w + (size_t)layer * H * H, hwbuf);
        agg_kernel<<<wgrid, 256, 0, stream>>>(hwbuf, row_off, srcs, wnorm, dinv,
                                              conv_b + (size_t)layer * H, hbuf);
    }

    // decoder
    decoder_kernel<<<wgrid, 256, 0, stream>>>(hbuf, dec_w, dec_b, out);
}

// Round 15
// 678.434 us; speedup vs baseline: 1.1986x; 1.0181x over previous
//
#include <hip/hip_runtime.h>
#include <hip/hip_bf16.h>

// Problem constants (from reference)
constexpr int NN = 50000;   // nodes
constexpr int EE = 800000;  // edges
constexpr int D_IN = 16;
constexpr int H = 128;
constexpr int D_OUT = 3;
constexpr int NB = (NN + 255) / 256;  // 196 scan blocks

// ---------------------------------------------------------------------------
// K0: detect whether edge_index arrived as int64 (reference dtype) or int32.
// Values < 2^31, so an int64 buffer has ALL odd int32 words == 0; an int32
// buffer has random src values at odd positions. Device-side only (graph-safe).
__global__ __launch_bounds__(1024) void detect_kernel(const int* __restrict__ e,
                                                      int* __restrict__ flag) {
    __shared__ int any_nonzero;
    if (threadIdx.x == 0) any_nonzero = 0;
    __syncthreads();
    if (e[2 * threadIdx.x + 1] != 0) atomicOr(&any_nonzero, 1);
    __syncthreads();
    if (threadIdx.x == 0) *flag = (any_nonzero == 0) ? 1 : 0;  // 1 => int64
}

// K1: zero the per-node edge counters
__global__ __launch_bounds__(256) void zero_counts_kernel(int* __restrict__ counts) {
    int i = blockIdx.x * 256 + threadIdx.x;
    if (i < NN) counts[i] = 0;
}

// K2: count in-degree (dst side), excluding the synthetic self loop
__global__ __launch_bounds__(256) void count_kernel(const int* __restrict__ e,
                                                    const int* __restrict__ flag,
                                                    int* __restrict__ counts) {
    int i = blockIdx.x * 256 + threadIdx.x;
    if (i >= EE) return;
    int f = *flag;  // uniform, cached
    int d = f ? e[2 * EE + 2 * i] : e[EE + i];
    atomicAdd(&counts[d], 1);
}

// K3a: per-block sums of counts (coalesced; wave+LDS reduce)
__global__ __launch_bounds__(256) void block_sum_kernel(const int* __restrict__ counts,
                                                        int* __restrict__ blocksums) {
    int t = threadIdx.x;
    int i = blockIdx.x * 256 + t;
    int c = (i < NN) ? counts[i] : 0;
#pragma unroll
    for (int off = 32; off >= 1; off >>= 1) c += __shfl_down(c, off, 64);
    __shared__ int ws[4];
    if ((t & 63) == 0) ws[t >> 6] = c;
    __syncthreads();
    if (t == 0) blocksums[blockIdx.x] = ws[0] + ws[1] + ws[2] + ws[3];
}

// K3b: single-block scan over the 196 block sums -> exclusive block offsets
__global__ __launch_bounds__(256) void block_scan_kernel(const int* __restrict__ blocksums,
                                                         int* __restrict__ blockoff,
                                                         int* __restrict__ row_off) {
    __shared__ int lds[256];
    int t = threadIdx.x;
    int s = (t < NB) ? blocksums[t] : 0;
    lds[t] = s;
    __syncthreads();
    for (int off = 1; off < 256; off <<= 1) {
        int v = (t >= off) ? lds[t - off] : 0;
        __syncthreads();
        lds[t] += v;
        __syncthreads();
    }
    if (t < NB) blockoff[t] = lds[t] - s;   // exclusive
    if (t == 255) row_off[NN] = lds[255];   // == EE
}

// K3c: per-block local exclusive scan + block offset -> row_off/fill_pos/dinv
__global__ __launch_bounds__(256) void block_scan_apply_kernel(const int* __restrict__ counts,
                                                               const int* __restrict__ blockoff,
                                                               int* __restrict__ row_off,
                                                               int* __restrict__ fill_pos,
                                                               float* __restrict__ dinv) {
    __shared__ int lds[256];
    int t = threadIdx.x;
    int i = blockIdx.x * 256 + t;
    int c = (i < NN) ? counts[i] : 0;
    lds[t] = c;
    __syncthreads();
    for (int off = 1; off < 256; off <<= 1) {
        int v = (t >= off) ? lds[t - off] : 0;
        __syncthreads();
        lds[t] += v;
        __syncthreads();
    }
    if (i < NN) {
        int excl = lds[t] - c + blockoff[blockIdx.x];
        row_off[i] = excl;
        fill_pos[i] = excl;
        dinv[i] = rsqrtf((float)(c + 1));  // +1 = self loop; deg >= 1 always
    }
}

// K4: scatter edges into CSR buckets; precompute per-edge weight dinv[s]*dinv[d].
// (order within bucket nondeterministic; fp32 sum order tolerance OK)
__global__ __launch_bounds__(256) void fill_kernel(const int* __restrict__ e,
                                                   const int* __restrict__ flag,
                                                   int* __restrict__ fill_pos,
                                                   const float* __restrict__ dinv,
                                                   int* __restrict__ srcs,
                                                   float* __restrict__ wnorm) {
    int i = blockIdx.x * 256 + threadIdx.x;
    if (i >= EE) return;
    int f = *flag;
    int s = f ? e[2 * i]            : e[i];
    int d = f ? e[2 * EE + 2 * i]   : e[EE + i];
    int pos = atomicAdd(&fill_pos[d], 1);
    srcs[pos] = s;
    wnorm[pos] = dinv[s] * dinv[d];
}

// K5: encoder  h[n][j] = x[n][:] . enc_w[j][:] + enc_b[j]
// 32 nodes per block; W/bias/x all staged in LDS (x traffic exact, w ~12 MB total).
constexpr int ENC_NPB = 32;
__global__ __launch_bounds__(256) void encoder_kernel(const float* __restrict__ x,
                                                      const float* __restrict__ w,
                                                      const float* __restrict__ b,
                                                      float* __restrict__ h) {
    __shared__ float wt[D_IN][H];        // transposed: wt[k][j]
    __shared__ float bs[H];
    __shared__ float xs[ENC_NPB][D_IN];
    int t = threadIdx.x;
    for (int i = t; i < H * D_IN; i += 256) {
        int j = i >> 4, k = i & 15;
        wt[k][j] = w[i];
    }
    if (t < H) bs[t] = b[t];
    int n0 = blockIdx.x * ENC_NPB;
    // coalesced x stage: 512 consecutive floats
    for (int i = t; i < ENC_NPB * D_IN; i += 256) {
        int n = n0 + (i >> 4);
        xs[i >> 4][i & 15] = (n < NN) ? x[(size_t)n0 * D_IN + i] : 0.f;
    }
    __syncthreads();
    int j = t & 127;      // feature
    int half = t >> 7;    // 0/1
    for (int r = half; r < ENC_NPB; r += 2) {
        int n = n0 + r;
        if (n >= NN) break;
        float acc = bs[j];
#pragma unroll
        for (int k = 0; k < D_IN; ++k) acc += xs[r][k] * wt[k][j];
        h[(size_t)n * H + j] = acc;
    }
}

// K6: conv GEMM  hw = h @ W^T   (W: [H][H] row-major)
// 32 rows/block, 256 threads, 4x4 register tile.
// h-tile in LDS row-major [32][132] (+4 pad): staging is one conflict-free
// ds_write_b128/thread; fragment reads are half-wave-broadcast ds_read_b128
// (2 distinct addrs/wave, 16-bank offset -> conflict-free). Fixes the 3M
// SQ_LDS_BANK_CONFLICT of the transposed [128][36] layout (16-way on stores).
__global__ __launch_bounds__(256) void gemm_h_kernel(const float* __restrict__ hin,
                                                     const float* __restrict__ w,
                                                     float* __restrict__ hw) {
    __shared__ float ht[32][132];
    int t = threadIdx.x;
    int n0 = blockIdx.x * 32;
#pragma unroll
    for (int i = 0; i < 4; ++i) {
        int idx = t + i * 256;      // 0..1023
        int row = idx >> 5;         // 0..31
        int c4 = (idx & 31) << 2;   // 0,4,..,124
        int n = n0 + row;
        float4 v = make_float4(0.f, 0.f, 0.f, 0.f);
        if (n < NN) v = *reinterpret_cast<const float4*>(hin + (size_t)n * H + c4);
        *reinterpret_cast<float4*>(&ht[row][c4]) = v;  // dense b128, conflict-free
    }
    __syncthreads();
    int tx = t & 31, ty = t >> 5;
    int j0 = tx << 2, r0 = ty << 2;  // 4 output cols, 4 rows per thread
    float acc[4][4] = {};            // acc[ri][ji]
    const float* wbase = w + j0 * H;
#pragma unroll 2
    for (int k = 0; k < 128; k += 4) {
        float4 av[4];  // av[ri] = ht[r0+ri][k..k+3]
#pragma unroll
        for (int ri = 0; ri < 4; ++ri)
            av[ri] = *reinterpret_cast<const float4*>(&ht[r0 + ri][k]);
#pragma unroll
        for (int ji = 0; ji < 4; ++ji) {
            float4 wv = *reinterpret_cast<const float4*>(wbase + ji * H + k);
#pragma unroll
            for (int ri = 0; ri < 4; ++ri)
                acc[ri][ji] += av[ri].x * wv.x + av[ri].y * wv.y +
                               av[ri].z * wv.z + av[ri].w * wv.w;
        }
    }
#pragma unroll
    for (int ri = 0; ri < 4; ++ri) {
        int n = n0 + r0 + ri;
        if (n < NN)
            *reinterpret_cast<float4*>(hw + (size_t)n * H + j0) =
                make_float4(acc[ri][0], acc[ri][1], acc[ri][2], acc[ri][3]);
    }
}

// K7: aggregation. One wave per node; lane owns features {2*lane, 2*lane+1} (float2).
// Fuses: edge gather+scale (precomputed wnorm), self-loop term, bias, ReLU.
// No atomics, no zeroing. unroll-4: batch index/weight loads -> 4 independent
// gathers in flight per wave (dependent-chain latency hiding).
__global__ __launch_bounds__(256) void agg_kernel(const float* __restrict__ hw,
                                                  const int* __restrict__ row_off,
                                                  const int* __restrict__ srcs,
                                                  const float* __restrict__ wnorm,
                                                  const float* __restrict__ dinv,
                                                  const float* __restrict__ b,
                                                  float* __restrict__ hout) {
    int wid = (blockIdx.x * 256 + threadIdx.x) >> 6;  // node id
    int lane = threadIdx.x & 63;
    if (wid >= NN) return;
    const float2* hw2 = reinterpret_cast<const float2*>(hw);
    float dn = dinv[wid];
    float2 v = hw2[(size_t)wid * 64 + lane];
    float a0 = v.x * dn * dn;                 // appended self loop
    float a1 = v.y * dn * dn;
    int beg = row_off[wid], end = row_off[wid + 1];
#pragma unroll 4
    for (int j = beg; j < end; ++j) {
        int s = srcs[j];                        // wave-uniform streamed load
        float wgt = wnorm[j];                   // wave-uniform streamed load
        float2 u = hw2[(size_t)s * 64 + lane];  // 512B/wave coalesced gather
        a0 += wgt * u.x;
        a1 += wgt * u.y;
    }
    float2 bb = reinterpret_cast<const float2*>(b)[lane];
    float2 o;
    o.x = fmaxf(a0 + bb.x, 0.f);
    o.y = fmaxf(a1 + bb.y, 0.f);
    reinterpret_cast<float2*>(hout)[(size_t)wid * 64 + lane] = o;
}

// K8: decoder  out[n][k] = h[n][:] . dec_w[k][:] + dec_b[k]; one wave per node
__global__ __launch_bounds__(256) void decoder_kernel(const float* __restrict__ h,
                                                      const float* __restrict__ w,
                                                      const float* __restrict__ b,
                                                      float* __restrict__ out) {
    int wid = (blockIdx.x * 256 + threadIdx.x) >> 6;
    int lane = threadIdx.x & 63;
    if (wid >= NN) return;
    float h0 = h[(size_t)wid * H + lane];
    float h1 = h[(size_t)wid * H + lane + 64];
    float p0 = h0 * w[0 * H + lane] + h1 * w[0 * H + lane + 64];
    float p1 = h0 * w[1 * H + lane] + h1 * w[1 * H + lane + 64];
    float p2 = h0 * w[2 * H + lane] + h1 * w[2 * H + lane + 64];
#pragma unroll
    for (int off = 32; off >= 1; off >>= 1) {
        p0 += __shfl_down(p0, off, 64);
        p1 += __shfl_down(p1, off, 64);
        p2 += __shfl_down(p2, off, 64);
    }
    if (lane == 0) {
        out[wid * 3 + 0] = p0 + b[0];
        out[wid * 3 + 1] = p1 + b[1];
        out[wid * 3 + 2] = p2 + b[2];
    }
}

extern "C" void kernel_launch(void* const* d_in, const int* in_sizes, int n_in,
                              void* d_out, int out_size, void* d_ws, size_t ws_size,
                              hipStream_t stream) {
    const float* x      = (const float*)d_in[0];
    const int*   eidx   = (const int*)d_in[1];   // [2][E]; int32 or int64 (detected)
    const float* enc_w  = (const float*)d_in[2];
    const float* enc_b  = (const float*)d_in[3];
    const float* conv_w = (const float*)d_in[4]; // [3][H][H]
    const float* conv_b = (const float*)d_in[5]; // [3][H]
    const float* dec_w  = (const float*)d_in[6];
    const float* dec_b  = (const float*)d_in[7];
    float* out = (float*)d_out;

    // workspace carve-out (256B aligned); total ~59 MB
    char* ws = (char*)d_ws;
    auto alloc = [&](size_t bytes) -> char* {
        char* p = ws;
        ws += (bytes + 255) & ~(size_t)255;
        return p;
    };
    int*   flag      = (int*)alloc(256);
    int*   counts    = (int*)alloc((size_t)NN * 4);
    int*   blocksums = (int*)alloc((size_t)NB * 4);
    int*   blockoff  = (int*)alloc((size_t)NB * 4);
    int*   row_off   = (int*)alloc((size_t)(NN + 1) * 4);
    int*   fill_pos  = (int*)alloc((size_t)NN * 4);
    float* dinv      = (float*)alloc((size_t)NN * 4);
    int*   srcs      = (int*)alloc((size_t)EE * 4);
    float* wnorm     = (float*)alloc((size_t)EE * 4);
    float* hbuf      = (float*)alloc((size_t)NN * H * 4);
    float* hwbuf     = (float*)alloc((size_t)NN * H * 4);

    const int egrid = (EE + 255) / 256;          // 3125
    const int wgrid = (NN + 3) / 4;              // 12500 (4 waves/block)

    // CSR build (once; reused by all 3 layers)
    detect_kernel<<<1, 1024, 0, stream>>>(eidx, flag);
    zero_counts_kernel<<<NB, 256, 0, stream>>>(counts);
    count_kernel<<<egrid, 256, 0, stream>>>(eidx, flag, counts);
    block_sum_kernel<<<NB, 256, 0, stream>>>(counts, blocksums);
    block_scan_kernel<<<1, 256, 0, stream>>>(blocksums, blockoff, row_off);
    block_scan_apply_kernel<<<NB, 256, 0, stream>>>(counts, blockoff, row_off, fill_pos, dinv);
    fill_kernel<<<egrid, 256, 0, stream>>>(eidx, flag, fill_pos, dinv, srcs, wnorm);

    // encoder
    encoder_kernel<<<(NN + ENC_NPB - 1) / ENC_NPB, 256, 0, stream>>>(x, enc_w, enc_b, hbuf);

    // 3 GCN layers: hbuf -> hwbuf (GEMM) -> hbuf (agg+relu)
    const int ggrid = (NN + 31) / 32;            // 1563
    for (int layer = 0; layer < 3; ++layer) {
        gemm_h_kernel<<<ggrid, 256, 0, stream>>>(hbuf, conv_w + (size_t)layer * H * H, hwbuf);
        agg_kernel<<<wgrid, 256, 0, stream>>>(hwbuf, row_off, srcs, wnorm, dinv,
                                              conv_b + (size_t)layer * H, hbuf);
    }

    // decoder
    decoder_kernel<<<wgrid, 256, 0, stream>>>(hbuf, dec_w, dec_b, out);
}

// Round 18
// 476.041 us; speedup vs baseline: 1.7082x; 1.4252x over previous
//
#include <hip/hip_runtime.h>
#include <hip/hip_bf16.h>

// Problem constants (from reference)
constexpr int NN = 50000;   // nodes
constexpr int EE = 800000;  // edges
constexpr int D_IN = 16;
constexpr int H = 128;
constexpr int D_OUT = 3;
constexpr int NB = (NN + 255) / 256;  // 196 scan blocks

// ---------------------------------------------------------------------------
// K0: detect whether edge_index arrived as int64 (reference dtype) or int32.
// Values < 2^31, so an int64 buffer has ALL odd int32 words == 0; an int32
// buffer has random src values at odd positions. Device-side only (graph-safe).
__global__ __launch_bounds__(1024) void detect_kernel(const int* __restrict__ e,
                                                      int* __restrict__ flag) {
    __shared__ int any_nonzero;
    if (threadIdx.x == 0) any_nonzero = 0;
    __syncthreads();
    if (e[2 * threadIdx.x + 1] != 0) atomicOr(&any_nonzero, 1);
    __syncthreads();
    if (threadIdx.x == 0) *flag = (any_nonzero == 0) ? 1 : 0;  // 1 => int64
}

// K1: zero the per-node edge counters
__global__ __launch_bounds__(256) void zero_counts_kernel(int* __restrict__ counts) {
    int i = blockIdx.x * 256 + threadIdx.x;
    if (i < NN) counts[i] = 0;
}

// K2: count in-degree (dst side), excluding the synthetic self loop
__global__ __launch_bounds__(256) void count_kernel(const int* __restrict__ e,
                                                    const int* __restrict__ flag,
                                                    int* __restrict__ counts) {
    int i = blockIdx.x * 256 + threadIdx.x;
    if (i >= EE) return;
    int f = *flag;  // uniform, cached
    int d = f ? e[2 * EE + 2 * i] : e[EE + i];
    atomicAdd(&counts[d], 1);
}

// K3a: per-block sums of counts (coalesced; wave+LDS reduce)
__global__ __launch_bounds__(256) void block_sum_kernel(const int* __restrict__ counts,
                                                        int* __restrict__ blocksums) {
    int t = threadIdx.x;
    int i = blockIdx.x * 256 + t;
    int c = (i < NN) ? counts[i] : 0;
#pragma unroll
    for (int off = 32; off >= 1; off >>= 1) c += __shfl_down(c, off, 64);
    __shared__ int ws[4];
    if ((t & 63) == 0) ws[t >> 6] = c;
    __syncthreads();
    if (t == 0) blocksums[blockIdx.x] = ws[0] + ws[1] + ws[2] + ws[3];
}

// K3b: single-block scan over the 196 block sums -> exclusive block offsets
__global__ __launch_bounds__(256) void block_scan_kernel(const int* __restrict__ blocksums,
                                                         int* __restrict__ blockoff,
                                                         int* __restrict__ row_off) {
    __shared__ int lds[256];
    int t = threadIdx.x;
    int s = (t < NB) ? blocksums[t] : 0;
    lds[t] = s;
    __syncthreads();
    for (int off = 1; off < 256; off <<= 1) {
        int v = (t >= off) ? lds[t - off] : 0;
        __syncthreads();
        lds[t] += v;
        __syncthreads();
    }
    if (t < NB) blockoff[t] = lds[t] - s;   // exclusive
    if (t == 255) row_off[NN] = lds[255];   // == EE
}

// K3c: per-block local exclusive scan + block offset -> row_off/fill_pos/dinv
__global__ __launch_bounds__(256) void block_scan_apply_kernel(const int* __restrict__ counts,
                                                               const int* __restrict__ blockoff,
                                                               int* __restrict__ row_off,
                                                               int* __restrict__ fill_pos,
                                                               float* __restrict__ dinv) {
    __shared__ int lds[256];
    int t = threadIdx.x;
    int i = blockIdx.x * 256 + t;
    int c = (i < NN) ? counts[i] : 0;
    lds[t] = c;
    __syncthreads();
    for (int off = 1; off < 256; off <<= 1) {
        int v = (t >= off) ? lds[t - off] : 0;
        __syncthreads();
        lds[t] += v;
        __syncthreads();
    }
    if (i < NN) {
        int excl = lds[t] - c + blockoff[blockIdx.x];
        row_off[i] = excl;
        fill_pos[i] = excl;
        dinv[i] = rsqrtf((float)(c + 1));  // +1 = self loop; deg >= 1 always
    }
}

// K4: scatter edges into CSR buckets; precompute per-edge weight dinv[s]*dinv[d].
// (order within bucket nondeterministic; fp32 sum order tolerance OK)
__global__ __launch_bounds__(256) void fill_kernel(const int* __restrict__ e,
                                                   const int* __restrict__ flag,
                                                   int* __restrict__ fill_pos,
                                                   const float* __restrict__ dinv,
                                                   int* __restrict__ srcs,
                                                   float* __restrict__ wnorm) {
    int i = blockIdx.x * 256 + threadIdx.x;
    if (i >= EE) return;
    int f = *flag;
    int s = f ? e[2 * i]            : e[i];
    int d = f ? e[2 * EE + 2 * i]   : e[EE + i];
    int pos = atomicAdd(&fill_pos[d], 1);
    srcs[pos] = s;
    wnorm[pos] = dinv[s] * dinv[d];
}

// K5: encoder  h[n][j] = x[n][:] . enc_w[j][:] + enc_b[j]
// 32 nodes per block; W/bias/x all staged in LDS (x traffic exact, w ~12 MB total).
constexpr int ENC_NPB = 32;
__global__ __launch_bounds__(256) void encoder_kernel(const float* __restrict__ x,
                                                      const float* __restrict__ w,
                                                      const float* __restrict__ b,
                                                      float* __restrict__ h) {
    __shared__ float wt[D_IN][H];        // transposed: wt[k][j]
    __shared__ float bs[H];
    __shared__ float xs[ENC_NPB][D_IN];
    int t = threadIdx.x;
    for (int i = t; i < H * D_IN; i += 256) {
        int j = i >> 4, k = i & 15;
        wt[k][j] = w[i];
    }
    if (t < H) bs[t] = b[t];
    int n0 = blockIdx.x * ENC_NPB;
    // coalesced x stage: 512 consecutive floats
    for (int i = t; i < ENC_NPB * D_IN; i += 256) {
        int n = n0 + (i >> 4);
        xs[i >> 4][i & 15] = (n < NN) ? x[(size_t)n0 * D_IN + i] : 0.f;
    }
    __syncthreads();
    int j = t & 127;      // feature
    int half = t >> 7;    // 0/1
    for (int r = half; r < ENC_NPB; r += 2) {
        int n = n0 + r;
        if (n >= NN) break;
        float acc = bs[j];
#pragma unroll
        for (int k = 0; k < D_IN; ++k) acc += xs[r][k] * wt[k][j];
        h[(size_t)n * H + j] = acc;
    }
}

// K6: conv GEMM  hw = h @ W^T   (W: [H][H] row-major)
// 32 rows/block, 256 threads, 4x4 register tile. Both operands from LDS.
// R15 profile: conflicts=0 but dur unchanged (111us), VALUBusy 17% -> the real
// stall was the W global path: lane-stride 2KB scattered dwordx4 (32 lines/wave,
// 25% utilization, L1-thrashing, L2-latency-bound). Fix: stage W per 32-wide
// K-chunk through LDS with coalesced loads + transposed write wt[kk][j].
// ht reads: half-wave broadcast (conflict-free). wt reads: ~4-way (benign).
// LDS 33.8KB -> 4 blocks/CU (16 waves/CU).
__global__ __launch_bounds__(256) void gemm_h_kernel(const float* __restrict__ hin,
                                                     const float* __restrict__ w,
                                                     float* __restrict__ hw) {
    __shared__ float ht[32][132];
    __shared__ float wt[32][132];  // wt[kk][j] = W[j][k0+kk] for current chunk
    int t = threadIdx.x;
    int n0 = blockIdx.x * 32;
#pragma unroll
    for (int i = 0; i < 4; ++i) {
        int idx = t + i * 256;      // 0..1023
        int row = idx >> 5;         // 0..31
        int c4 = (idx & 31) << 2;   // 0,4,..,124
        int n = n0 + row;
        float4 v = make_float4(0.f, 0.f, 0.f, 0.f);
        if (n < NN) v = *reinterpret_cast<const float4*>(hin + (size_t)n * H + c4);
        *reinterpret_cast<float4*>(&ht[row][c4]) = v;  // dense b128, conflict-free
    }
    int tx = t & 31, ty = t >> 5;
    int j0 = tx << 2, r0 = ty << 2;  // 4 output cols, 4 rows per thread
    float acc[4][4] = {};            // acc[ri][ji]
    int wj = t >> 3;                 // 0..31 (base W row for staging)
    int wc4 = (t & 7) << 2;          // 0,4,..,28 (k offset within chunk)

    for (int k0 = 0; k0 < 128; k0 += 32) {
        __syncthreads();  // protect ht (first iter) / wt (prev chunk readers)
        // stage W[j][k0..k0+31] -> wt[kk][j]; coalesced 128B-contiguous reads
#pragma unroll
        for (int i = 0; i < 4; ++i) {
            int j = wj + i * 32;     // 0..127, each (j,wc4) exactly once
            float4 v = *reinterpret_cast<const float4*>(w + (size_t)j * H + k0 + wc4);
            wt[wc4 + 0][j] = v.x;
            wt[wc4 + 1][j] = v.y;
            wt[wc4 + 2][j] = v.z;
            wt[wc4 + 3][j] = v.w;
        }
        __syncthreads();
#pragma unroll 2
        for (int kk = 0; kk < 32; kk += 4) {
            float4 av[4];   // av[ri] = ht[r0+ri][k0+kk..+3] (broadcast read)
#pragma unroll
            for (int ri = 0; ri < 4; ++ri)
                av[ri] = *reinterpret_cast<const float4*>(&ht[r0 + ri][k0 + kk]);
            float wv[4][4]; // wv[m][ji] = W[j0+ji][k0+kk+m]
#pragma unroll
            for (int m = 0; m < 4; ++m)
                *reinterpret_cast<float4*>(wv[m]) =
                    *reinterpret_cast<const float4*>(&wt[kk + m][j0]);
#pragma unroll
            for (int ji = 0; ji < 4; ++ji)
#pragma unroll
                for (int ri = 0; ri < 4; ++ri)
                    acc[ri][ji] += av[ri].x * wv[0][ji] + av[ri].y * wv[1][ji] +
                                   av[ri].z * wv[2][ji] + av[ri].w * wv[3][ji];
        }
    }
#pragma unroll
    for (int ri = 0; ri < 4; ++ri) {
        int n = n0 + r0 + ri;
        if (n < NN)
            *reinterpret_cast<float4*>(hw + (size_t)n * H + j0) =
                make_float4(acc[ri][0], acc[ri][1], acc[ri][2], acc[ri][3]);
    }
}

// K7: aggregation. One wave per node; lane owns features {2*lane, 2*lane+1} (float2).
// Fuses: edge gather+scale (precomputed wnorm), self-loop term, bias, ReLU.
// No atomics, no zeroing. unroll-4: batch index/weight loads -> 4 independent
// gathers in flight per wave (dependent-chain latency hiding).
__global__ __launch_bounds__(256) void agg_kernel(const float* __restrict__ hw,
                                                  const int* __restrict__ row_off,
                                                  const int* __restrict__ srcs,
                                                  const float* __restrict__ wnorm,
                                                  const float* __restrict__ dinv,
                                                  const float* __restrict__ b,
                                                  float* __restrict__ hout) {
    int wid = (blockIdx.x * 256 + threadIdx.x) >> 6;  // node id
    int lane = threadIdx.x & 63;
    if (wid >= NN) return;
    const float2* hw2 = reinterpret_cast<const float2*>(hw);
    float dn = dinv[wid];
    float2 v = hw2[(size_t)wid * 64 + lane];
    float a0 = v.x * dn * dn;                 // appended self loop
    float a1 = v.y * dn * dn;
    int beg = row_off[wid], end = row_off[wid + 1];
#pragma unroll 4
    for (int j = beg; j < end; ++j) {
        int s = srcs[j];                        // wave-uniform streamed load
        float wgt = wnorm[j];                   // wave-uniform streamed load
        float2 u = hw2[(size_t)s * 64 + lane];  // 512B/wave coalesced gather
        a0 += wgt * u.x;
        a1 += wgt * u.y;
    }
    float2 bb = reinterpret_cast<const float2*>(b)[lane];
    float2 o;
    o.x = fmaxf(a0 + bb.x, 0.f);
    o.y = fmaxf(a1 + bb.y, 0.f);
    reinterpret_cast<float2*>(hout)[(size_t)wid * 64 + lane] = o;
}

// K8: decoder  out[n][k] = h[n][:] . dec_w[k][:] + dec_b[k]; one wave per node
__global__ __launch_bounds__(256) void decoder_kernel(const float* __restrict__ h,
                                                      const float* __restrict__ w,
                                                      const float* __restrict__ b,
                                                      float* __restrict__ out) {
    int wid = (blockIdx.x * 256 + threadIdx.x) >> 6;
    int lane = threadIdx.x & 63;
    if (wid >= NN) return;
    float h0 = h[(size_t)wid * H + lane];
    float h1 = h[(size_t)wid * H + lane + 64];
    float p0 = h0 * w[0 * H + lane] + h1 * w[0 * H + lane + 64];
    float p1 = h0 * w[1 * H + lane] + h1 * w[1 * H + lane + 64];
    float p2 = h0 * w[2 * H + lane] + h1 * w[2 * H + lane + 64];
#pragma unroll
    for (int off = 32; off >= 1; off >>= 1) {
        p0 += __shfl_down(p0, off, 64);
        p1 += __shfl_down(p1, off, 64);
        p2 += __shfl_down(p2, off, 64);
    }
    if (lane == 0) {
        out[wid * 3 + 0] = p0 + b[0];
        out[wid * 3 + 1] = p1 + b[1];
        out[wid * 3 + 2] = p2 + b[2];
    }
}

extern "C" void kernel_launch(void* const* d_in, const int* in_sizes, int n_in,
                              void* d_out, int out_size, void* d_ws, size_t ws_size,
                              hipStream_t stream) {
    const float* x      = (const float*)d_in[0];
    const int*   eidx   = (const int*)d_in[1];   // [2][E]; int32 or int64 (detected)
    const float* enc_w  = (const float*)d_in[2];
    const float* enc_b  = (const float*)d_in[3];
    const float* conv_w = (const float*)d_in[4]; // [3][H][H]
    const float* conv_b = (const float*)d_in[5]; // [3][H]
    const float* dec_w  = (const float*)d_in[6];
    const float* dec_b  = (const float*)d_in[7];
    float* out = (float*)d_out;

    // workspace carve-out (256B aligned); total ~59 MB
    char* ws = (char*)d_ws;
    auto alloc = [&](size_t bytes) -> char* {
        char* p = ws;
        ws += (bytes + 255) & ~(size_t)255;
        return p;
    };
    int*   flag      = (int*)alloc(256);
    int*   counts    = (int*)alloc((size_t)NN * 4);
    int*   blocksums = (int*)alloc((size_t)NB * 4);
    int*   blockoff  = (int*)alloc((size_t)NB * 4);
    int*   row_off   = (int*)alloc((size_t)(NN + 1) * 4);
    int*   fill_pos  = (int*)alloc((size_t)NN * 4);
    float* dinv      = (float*)alloc((size_t)NN * 4);
    int*   srcs      = (int*)alloc((size_t)EE * 4);
    float* wnorm     = (float*)alloc((size_t)EE * 4);
    float* hbuf      = (float*)alloc((size_t)NN * H * 4);
    float* hwbuf     = (float*)alloc((size_t)NN * H * 4);

    const int egrid = (EE + 255) / 256;          // 3125
    const int wgrid = (NN + 3) / 4;              // 12500 (4 waves/block)

    // CSR build (once; reused by all 3 layers)
    detect_kernel<<<1, 1024, 0, stream>>>(eidx, flag);
    zero_counts_kernel<<<NB, 256, 0, stream>>>(counts);
    count_kernel<<<egrid, 256, 0, stream>>>(eidx, flag, counts);
    block_sum_kernel<<<NB, 256, 0, stream>>>(counts, blocksums);
    block_scan_kernel<<<1, 256, 0, stream>>>(blocksums, blockoff, row_off);
    block_scan_apply_kernel<<<NB, 256, 0, stream>>>(counts, blockoff, row_off, fill_pos, dinv);
    fill_kernel<<<egrid, 256, 0, stream>>>(eidx, flag, fill_pos, dinv, srcs, wnorm);

    // encoder
    encoder_kernel<<<(NN + ENC_NPB - 1) / ENC_NPB, 256, 0, stream>>>(x, enc_w, enc_b, hbuf);

    // 3 GCN layers: hbuf -> hwbuf (GEMM) -> hbuf (agg+relu)
    const int ggrid = (NN + 31) / 32;            // 1563
    for (int layer = 0; layer < 3; ++layer) {
        gemm_h_kernel<<<ggrid, 256, 0, stream>>>(hbuf, conv_w + (size_t)layer * H * H, hwbuf);
        agg_kernel<<<wgrid, 256, 0, stream>>>(hwbuf, row_off, srcs, wnorm, dinv,
                                              conv_b + (size_t)layer * H, hbuf);
    }

    // decoder
    decoder_kernel<<<wgrid, 256, 0, stream>>>(hbuf, dec_w, dec_b, out);
}